// Round 2
// baseline (552.910 us; speedup 1.0000x reference)
//
#include <hip/hip_runtime.h>
#include <hip/hip_bf16.h>

#define NHEADS 16
#define HDIM 64
#define BATCH 4
#define SEQ 2048
#define CDIM 1024
#define ROWS (BATCH * SEQ)  // 8192

typedef __attribute__((ext_vector_type(8))) short short8;
typedef __attribute__((ext_vector_type(4))) float f32x4;

__device__ inline short f2bf(float f) {
    unsigned int u = __builtin_bit_cast(unsigned int, f);
    unsigned int r = (u + 0x7fffu + ((u >> 16) & 1u)) >> 16;
    return (short)r;
}

// ---------------------------------------------------------------------------
// GEMM (fp32 in, bf16 MFMA, fp32 acc) 128x128 tile + bias + fused per-head
// LayerNorm. Each wave computes a 64x64 sub-tile; head dim = 64 => LN
// reduction is wave-local (shuffle over 16 lanes, sum over 4 col-tiles).
// ---------------------------------------------------------------------------
__global__ __launch_bounds__(256) void gemm_q_ln(
    const float* __restrict__ X,     // [8192][1024] fp32
    const float* __restrict__ W,     // [1024][1024] fp32
    const float* __restrict__ bias,  // [1024]
    const float* __restrict__ gamma, // [64]
    const float* __restrict__ beta,  // [64]
    short* __restrict__ Out)         // [B][H][N][64] bf16
{
    __shared__ short As[128][40];
    __shared__ short Bt[128][40];

    const int tid = threadIdx.x;
    const int wave = tid >> 6, lane = tid & 63;
    const int wr = wave >> 1, wc = wave & 1;
    const int quad = lane >> 4, l15 = lane & 15;
    const int rblk = blockIdx.y, cblk = blockIdx.x;
    const int K = CDIM, NW = CDIM;

    f32x4 acc[4][4];
#pragma unroll
    for (int i = 0; i < 4; i++)
#pragma unroll
        for (int j = 0; j < 4; j++) acc[i][j] = f32x4{0.f, 0.f, 0.f, 0.f};

    const int arow = tid >> 1, acol = (tid & 1) * 16;
    const int bkr = tid >> 3, bnc = (tid & 7) * 16;

    for (int k0 = 0; k0 < K; k0 += 32) {
        const float* pa = X + (size_t)(rblk * 128 + arow) * K + k0 + acol;
        float av[16];
#pragma unroll
        for (int e = 0; e < 16; e += 4) {
            f32x4 t = *(const f32x4*)(pa + e);
            av[e] = t[0]; av[e + 1] = t[1]; av[e + 2] = t[2]; av[e + 3] = t[3];
        }
        const float* pb = W + (size_t)(k0 + bkr) * NW + cblk * 128 + bnc;
        float bvv[16];
#pragma unroll
        for (int e = 0; e < 16; e += 4) {
            f32x4 t = *(const f32x4*)(pb + e);
            bvv[e] = t[0]; bvv[e + 1] = t[1]; bvv[e + 2] = t[2]; bvv[e + 3] = t[3];
        }

        short8 a0, a1;
#pragma unroll
        for (int e = 0; e < 8; e++) { a0[e] = f2bf(av[e]); a1[e] = f2bf(av[8 + e]); }

        __syncthreads();
        *(short8*)&As[arow][acol] = a0;
        *(short8*)&As[arow][acol + 8] = a1;
#pragma unroll
        for (int e = 0; e < 16; e++) Bt[bnc + e][bkr] = f2bf(bvv[e]);
        __syncthreads();

        short8 af[4], bfr[4];
#pragma unroll
        for (int i = 0; i < 4; i++)
            af[i] = *(const short8*)&As[wr * 64 + i * 16 + l15][quad * 8];
#pragma unroll
        for (int j = 0; j < 4; j++)
            bfr[j] = *(const short8*)&Bt[wc * 64 + j * 16 + l15][quad * 8];
#pragma unroll
        for (int i = 0; i < 4; i++)
#pragma unroll
            for (int j = 0; j < 4; j++)
                acc[i][j] = __builtin_amdgcn_mfma_f32_16x16x32_bf16(af[i], bfr[j], acc[i][j], 0, 0, 0);
    }

    // epilogue: bias + per-head LayerNorm (cols of this wave == one head)
    const int col0 = cblk * 128 + wc * 64;
    const int h = col0 >> 6;
    float bv[4], gv[4], btv[4];
#pragma unroll
    for (int j = 0; j < 4; j++) {
        int d = j * 16 + l15;
        bv[j] = bias[col0 + d];
        gv[j] = gamma[d];
        btv[j] = beta[d];
    }
#pragma unroll
    for (int i = 0; i < 4; i++) {
        int rowl = rblk * 128 + wr * 64 + i * 16 + quad * 4;
#pragma unroll
        for (int reg = 0; reg < 4; reg++) {
            float x[4], s = 0.f, s2 = 0.f;
#pragma unroll
            for (int j = 0; j < 4; j++) {
                x[j] = acc[i][j][reg] + bv[j];
                s += x[j];
                s2 += x[j] * x[j];
            }
#pragma unroll
            for (int m = 1; m < 16; m <<= 1) {
                s += __shfl_xor(s, m);
                s2 += __shfl_xor(s2, m);
            }
            float mean = s * (1.f / 64.f);
            float var = s2 * (1.f / 64.f) - mean * mean;
            float rstd = rsqrtf(var + 1e-5f);
            int r = rowl + reg;
            int b = r >> 11, n = r & (SEQ - 1);
            size_t base = (((size_t)b * NHEADS + h) * SEQ + n) * 64;
#pragma unroll
            for (int j = 0; j < 4; j++) {
                float y = (x[j] - mean) * rstd * gv[j] + btv[j];
                Out[base + j * 16 + l15] = f2bf(y);
            }
        }
    }
}

// KV variant: N=2048; col groups 0..15 = K (LN), 16..31 = V (bias only)
__global__ __launch_bounds__(256) void gemm_kv(
    const float* __restrict__ X,     // [8192][1024]
    const float* __restrict__ W,     // [1024][2048]
    const float* __restrict__ bias,  // [2048]
    const float* __restrict__ gamma, // [64]
    const float* __restrict__ beta,  // [64]
    short* __restrict__ KOut,        // [B][H][N][64] bf16
    short* __restrict__ VOut)        // [B][H][N][64] bf16
{
    __shared__ short As[128][40];
    __shared__ short Bt[128][40];

    const int tid = threadIdx.x;
    const int wave = tid >> 6, lane = tid & 63;
    const int wr = wave >> 1, wc = wave & 1;
    const int quad = lane >> 4, l15 = lane & 15;
    const int rblk = blockIdx.y, cblk = blockIdx.x;
    const int K = CDIM, NW = 2 * CDIM;

    f32x4 acc[4][4];
#pragma unroll
    for (int i = 0; i < 4; i++)
#pragma unroll
        for (int j = 0; j < 4; j++) acc[i][j] = f32x4{0.f, 0.f, 0.f, 0.f};

    const int arow = tid >> 1, acol = (tid & 1) * 16;
    const int bkr = tid >> 3, bnc = (tid & 7) * 16;

    for (int k0 = 0; k0 < K; k0 += 32) {
        const float* pa = X + (size_t)(rblk * 128 + arow) * K + k0 + acol;
        float av[16];
#pragma unroll
        for (int e = 0; e < 16; e += 4) {
            f32x4 t = *(const f32x4*)(pa + e);
            av[e] = t[0]; av[e + 1] = t[1]; av[e + 2] = t[2]; av[e + 3] = t[3];
        }
        const float* pb = W + (size_t)(k0 + bkr) * NW + cblk * 128 + bnc;
        float bvv[16];
#pragma unroll
        for (int e = 0; e < 16; e += 4) {
            f32x4 t = *(const f32x4*)(pb + e);
            bvv[e] = t[0]; bvv[e + 1] = t[1]; bvv[e + 2] = t[2]; bvv[e + 3] = t[3];
        }

        short8 a0, a1;
#pragma unroll
        for (int e = 0; e < 8; e++) { a0[e] = f2bf(av[e]); a1[e] = f2bf(av[8 + e]); }

        __syncthreads();
        *(short8*)&As[arow][acol] = a0;
        *(short8*)&As[arow][acol + 8] = a1;
#pragma unroll
        for (int e = 0; e < 16; e++) Bt[bnc + e][bkr] = f2bf(bvv[e]);
        __syncthreads();

        short8 af[4], bfr[4];
#pragma unroll
        for (int i = 0; i < 4; i++)
            af[i] = *(const short8*)&As[wr * 64 + i * 16 + l15][quad * 8];
#pragma unroll
        for (int j = 0; j < 4; j++)
            bfr[j] = *(const short8*)&Bt[wc * 64 + j * 16 + l15][quad * 8];
#pragma unroll
        for (int i = 0; i < 4; i++)
#pragma unroll
            for (int j = 0; j < 4; j++)
                acc[i][j] = __builtin_amdgcn_mfma_f32_16x16x32_bf16(af[i], bfr[j], acc[i][j], 0, 0, 0);
    }

    const int col0 = cblk * 128 + wc * 64;
    const int g = col0 >> 6;  // 0..31, wave-uniform
    float bv[4], gv[4], btv[4];
#pragma unroll
    for (int j = 0; j < 4; j++) {
        int d = j * 16 + l15;
        bv[j] = bias[col0 + d];
        gv[j] = gamma[d];
        btv[j] = beta[d];
    }

    if (g < NHEADS) {  // K path with LayerNorm
        const int h = g;
#pragma unroll
        for (int i = 0; i < 4; i++) {
            int rowl = rblk * 128 + wr * 64 + i * 16 + quad * 4;
#pragma unroll
            for (int reg = 0; reg < 4; reg++) {
                float x[4], s = 0.f, s2 = 0.f;
#pragma unroll
                for (int j = 0; j < 4; j++) {
                    x[j] = acc[i][j][reg] + bv[j];
                    s += x[j];
                    s2 += x[j] * x[j];
                }
#pragma unroll
                for (int m = 1; m < 16; m <<= 1) {
                    s += __shfl_xor(s, m);
                    s2 += __shfl_xor(s2, m);
                }
                float mean = s * (1.f / 64.f);
                float var = s2 * (1.f / 64.f) - mean * mean;
                float rstd = rsqrtf(var + 1e-5f);
                int r = rowl + reg;
                int b = r >> 11, n = r & (SEQ - 1);
                size_t base = (((size_t)b * NHEADS + h) * SEQ + n) * 64;
#pragma unroll
                for (int j = 0; j < 4; j++) {
                    float y = (x[j] - mean) * rstd * gv[j] + btv[j];
                    KOut[base + j * 16 + l15] = f2bf(y);
                }
            }
        }
    } else {  // V path, bias only
        const int h = g - NHEADS;
#pragma unroll
        for (int i = 0; i < 4; i++) {
            int rowl = rblk * 128 + wr * 64 + i * 16 + quad * 4;
#pragma unroll
            for (int reg = 0; reg < 4; reg++) {
                int r = rowl + reg;
                int b = r >> 11, n = r & (SEQ - 1);
                size_t base = (((size_t)b * NHEADS + h) * SEQ + n) * 64;
#pragma unroll
                for (int j = 0; j < 4; j++)
                    VOut[base + j * 16 + l15] = f2bf(acc[i][j][reg] + bv[j]);
            }
        }
    }
}

// ---------------------------------------------------------------------------
// Flash attention: one block = 64 q-rows of one (b,h); 32 key-tiles of 64.
// S and O accumulators share the C/D row mapping (row = quad*4+reg), so
// online-softmax state (m, l, alpha) stays in registers. fp32 output.
// ---------------------------------------------------------------------------
__global__ __launch_bounds__(256) void attn_fa(
    const short* __restrict__ Q,  // [B][H][N][64] bf16
    const short* __restrict__ Kk, // [B][H][N][64] bf16
    const short* __restrict__ Vv, // [B][H][N][64] bf16
    float* __restrict__ Out)      // [B][N][1024] fp32
{
    __shared__ short Ks[64][72];
    __shared__ short Vt[64][72];  // transposed: [d][key]
    __shared__ short Ps[64][72];

    const int tid = threadIdx.x;
    const int wave = tid >> 6, lane = tid & 63;
    const int quad = lane >> 4, l15 = lane & 15;
    const int bh = blockIdx.y;
    const int b = bh >> 4, h = bh & 15;
    const int qt = blockIdx.x;
    const size_t head_base = (size_t)bh * SEQ * 64;

    // Q fragments (A operand): row = wave*16 + l15, k(d) = quad*8 + j (+32)
    const int qrow = qt * 64 + wave * 16 + l15;
    const short8 qf0 = *(const short8*)(Q + head_base + (size_t)qrow * 64 + quad * 8);
    const short8 qf1 = *(const short8*)(Q + head_base + (size_t)qrow * 64 + 32 + quad * 8);

    f32x4 o[4];
#pragma unroll
    for (int jd = 0; jd < 4; jd++) o[jd] = f32x4{0.f, 0.f, 0.f, 0.f};
    float mrow[4] = {-INFINITY, -INFINITY, -INFINITY, -INFINITY};
    float lrow[4] = {0.f, 0.f, 0.f, 0.f};

    const int skey = tid >> 2, sdg = (tid & 3) * 16;
    const float scale = 0.125f;  // 1/sqrt(64)

    for (int kt = 0; kt < 32; kt++) {
        const size_t kb = head_base + (size_t)(kt * 64 + skey) * 64 + sdg;
        short8 kv0 = *(const short8*)(Kk + kb);
        short8 kv1 = *(const short8*)(Kk + kb + 8);
        short8 vv0 = *(const short8*)(Vv + kb);
        short8 vv1 = *(const short8*)(Vv + kb + 8);

        __syncthreads();  // prior iteration's LDS reads done
        *(short8*)&Ks[skey][sdg] = kv0;
        *(short8*)&Ks[skey][sdg + 8] = kv1;
#pragma unroll
        for (int e = 0; e < 8; e++) {
            Vt[sdg + e][skey] = vv0[e];
            Vt[sdg + 8 + e][skey] = vv1[e];
        }
        __syncthreads();

        // S = Q K^T  (B operand: B[k=d][n=key] = Ks[key][d])
        f32x4 s[4];
#pragma unroll
        for (int jk = 0; jk < 4; jk++) {
            short8 kf0 = *(const short8*)&Ks[jk * 16 + l15][quad * 8];
            short8 kf1 = *(const short8*)&Ks[jk * 16 + l15][32 + quad * 8];
            f32x4 z = f32x4{0.f, 0.f, 0.f, 0.f};
            z = __builtin_amdgcn_mfma_f32_16x16x32_bf16(qf0, kf0, z, 0, 0, 0);
            z = __builtin_amdgcn_mfma_f32_16x16x32_bf16(qf1, kf1, z, 0, 0, 0);
            s[jk] = z;
        }
#pragma unroll
        for (int jk = 0; jk < 4; jk++)
#pragma unroll
            for (int reg = 0; reg < 4; reg++) s[jk][reg] *= scale;

        // online softmax (rows = quad*4+reg, reduce across 16 lanes)
        float alpha[4];
#pragma unroll
        for (int reg = 0; reg < 4; reg++) {
            float t = fmaxf(fmaxf(s[0][reg], s[1][reg]), fmaxf(s[2][reg], s[3][reg]));
#pragma unroll
            for (int m = 1; m < 16; m <<= 1) t = fmaxf(t, __shfl_xor(t, m));
            float mn = fmaxf(mrow[reg], t);
            alpha[reg] = __expf(mrow[reg] - mn);
            mrow[reg] = mn;
        }
#pragma unroll
        for (int reg = 0; reg < 4; reg++) {
            float acc = 0.f;
#pragma unroll
            for (int jk = 0; jk < 4; jk++) {
                float p = __expf(s[jk][reg] - mrow[reg]);
                s[jk][reg] = p;
                acc += p;
            }
#pragma unroll
            for (int m = 1; m < 16; m <<= 1) acc += __shfl_xor(acc, m);
            lrow[reg] = lrow[reg] * alpha[reg] + acc;
        }
#pragma unroll
        for (int jd = 0; jd < 4; jd++)
#pragma unroll
            for (int reg = 0; reg < 4; reg++) o[jd][reg] *= alpha[reg];

        // P: C-layout -> LDS -> A-layout
#pragma unroll
        for (int jk = 0; jk < 4; jk++)
#pragma unroll
            for (int reg = 0; reg < 4; reg++)
                Ps[wave * 16 + quad * 4 + reg][jk * 16 + l15] = f2bf(s[jk][reg]);
        __syncthreads();

        // O += P V   (B operand: B[k=key][n=d] = Vt[d][key])
        short8 pf0 = *(const short8*)&Ps[wave * 16 + l15][quad * 8];
        short8 pf1 = *(const short8*)&Ps[wave * 16 + l15][32 + quad * 8];
#pragma unroll
        for (int jd = 0; jd < 4; jd++) {
            short8 vf0 = *(const short8*)&Vt[jd * 16 + l15][quad * 8];
            short8 vf1 = *(const short8*)&Vt[jd * 16 + l15][32 + quad * 8];
            o[jd] = __builtin_amdgcn_mfma_f32_16x16x32_bf16(pf0, vf0, o[jd], 0, 0, 0);
            o[jd] = __builtin_amdgcn_mfma_f32_16x16x32_bf16(pf1, vf1, o[jd], 0, 0, 0);
        }
    }

    // epilogue: O / l, write [B][N][C] fp32
#pragma unroll
    for (int reg = 0; reg < 4; reg++) {
        float inv = 1.f / lrow[reg];
        int r = qt * 64 + wave * 16 + quad * 4 + reg;
        size_t base = ((size_t)b * SEQ + r) * CDIM + h * 64;
#pragma unroll
        for (int jd = 0; jd < 4; jd++)
            Out[base + jd * 16 + l15] = o[jd][reg] * inv;
    }
}

extern "C" void kernel_launch(void* const* d_in, const int* in_sizes, int n_in,
                              void* d_out, int out_size, void* d_ws, size_t ws_size,
                              hipStream_t stream) {
    const float* x1 = (const float*)d_in[0];
    const float* x2 = (const float*)d_in[1];
    const float* wq = (const float*)d_in[2];
    const float* bq = (const float*)d_in[3];
    const float* wkv = (const float*)d_in[4];
    const float* bkv = (const float*)d_in[5];
    const float* gq = (const float*)d_in[6];
    const float* btq = (const float*)d_in[7];
    const float* gk = (const float*)d_in[8];
    const float* btk = (const float*)d_in[9];
    float* out = (float*)d_out;

    short* qln = (short*)d_ws;                       // [B][H][N][64] bf16
    short* kln = qln + (size_t)ROWS * CDIM;          // [B][H][N][64]
    short* vv = kln + (size_t)ROWS * CDIM;           // [B][H][N][64]

    gemm_q_ln<<<dim3(8, 64), 256, 0, stream>>>(x1, wq, bq, gq, btq, qln);
    gemm_kv<<<dim3(16, 64), 256, 0, stream>>>(x2, wkv, bkv, gk, btk, kln, vv);
    attn_fa<<<dim3(32, 64), 256, 0, stream>>>(qln, kln, vv, out);
}

// Round 3
// 357.072 us; speedup vs baseline: 1.5485x; 1.5485x over previous
//
#include <hip/hip_runtime.h>
#include <hip/hip_bf16.h>

#define NHEADS 16
#define HDIM 64
#define BATCH 4
#define SEQ 2048
#define CDIM 1024
#define ROWS (BATCH * SEQ)  // 8192

typedef __attribute__((ext_vector_type(8))) short short8;
typedef __attribute__((ext_vector_type(4))) float f32x4;

__device__ inline short f2bf(float f) {
    unsigned int u = __builtin_bit_cast(unsigned int, f);
    unsigned int r = (u + 0x7fffu + ((u >> 16) & 1u)) >> 16;
    return (short)r;
}

__device__ __forceinline__ void gll16(const void* g, void* l) {
    __builtin_amdgcn_global_load_lds(
        (const __attribute__((address_space(1))) unsigned int*)g,
        (__attribute__((address_space(3))) unsigned int*)l, 16, 0, 0);
}

// ---------------------------------------------------------------------------
// Pre-pass 1: fp32 -> bf16 elementwise (x1, x2)
// ---------------------------------------------------------------------------
__global__ __launch_bounds__(256) void cvt_bf16(const float* __restrict__ src,
                                                short* __restrict__ dst, int n8) {
    int i = blockIdx.x * 256 + threadIdx.x;
    if (i < n8) {
        f32x4 a = ((const f32x4*)src)[i * 2];
        f32x4 b = ((const f32x4*)src)[i * 2 + 1];
        short8 o;
        o[0] = f2bf(a[0]); o[1] = f2bf(a[1]); o[2] = f2bf(a[2]); o[3] = f2bf(a[3]);
        o[4] = f2bf(b[0]); o[5] = f2bf(b[1]); o[6] = f2bf(b[2]); o[7] = f2bf(b[3]);
        ((short8*)dst)[i] = o;
    }
}

// ---------------------------------------------------------------------------
// Pre-pass 2: W [K=1024][Nw] fp32 -> W^T [Nw][1024] bf16 (64x64 LDS tiles)
// ---------------------------------------------------------------------------
__global__ __launch_bounds__(256) void wtrans(const float* __restrict__ W,
                                              short* __restrict__ WT, int Nw) {
    __shared__ short T[64][72];
    const int t = threadIdx.x;
    const int n0 = blockIdx.x * 64, k0 = blockIdx.y * 64;
    const int kl = t >> 2, c4 = (t & 3) * 16;
    const float* src = W + (size_t)(k0 + kl) * Nw + n0 + c4;
    short8 s0, s1;
#pragma unroll
    for (int e = 0; e < 2; e++) {
        f32x4 u = *(const f32x4*)(src + e * 4);
        s0[e * 4 + 0] = f2bf(u[0]); s0[e * 4 + 1] = f2bf(u[1]);
        s0[e * 4 + 2] = f2bf(u[2]); s0[e * 4 + 3] = f2bf(u[3]);
        f32x4 v = *(const f32x4*)(src + 8 + e * 4);
        s1[e * 4 + 0] = f2bf(v[0]); s1[e * 4 + 1] = f2bf(v[1]);
        s1[e * 4 + 2] = f2bf(v[2]); s1[e * 4 + 3] = f2bf(v[3]);
    }
    *(short8*)&T[kl][c4] = s0;
    *(short8*)&T[kl][c4 + 8] = s1;
    __syncthreads();
#pragma unroll
    for (int pass = 0; pass < 2; pass++) {
        int n = (t >> 3) + pass * 32;
        short8 o;
#pragma unroll
        for (int e = 0; e < 8; e++) o[e] = T[(t & 7) * 8 + e][n];
        *(short8*)(WT + (size_t)(n0 + n) * 1024 + k0 + (t & 7) * 8) = o;
    }
}

// ---------------------------------------------------------------------------
// GEMM (bf16 A, bf16 B^T, fp32 acc) m97-style: 128x128 tile, BK=32,
// global_load_lds staging, unpadded [128][32] LDS tiles.
// Q variant: + bias + per-head LayerNorm + 0.125 scale, out [B][H][N][64].
// ---------------------------------------------------------------------------
__global__ __launch_bounds__(256) void gemm_q_ln(
    const short* __restrict__ A,     // [8192][1024] bf16
    const short* __restrict__ BT,    // [1024][1024] bf16 (W^T)
    const float* __restrict__ bias,  // [1024]
    const float* __restrict__ gamma, // [64]
    const float* __restrict__ beta,  // [64]
    short* __restrict__ Out)         // [B][H][N][64] bf16 (pre-scaled by 1/8)
{
    __shared__ short As[128][32];
    __shared__ short Bs[128][32];

    const int tid = threadIdx.x;
    const int wave = tid >> 6, lane = tid & 63;
    const int wr = wave >> 1, wc = wave & 1;
    const int quad = lane >> 4, l15 = lane & 15;
    const int rblk = blockIdx.y, cblk = blockIdx.x;

    f32x4 acc[4][4];
#pragma unroll
    for (int i = 0; i < 4; i++)
#pragma unroll
        for (int j = 0; j < 4; j++) acc[i][j] = f32x4{0.f, 0.f, 0.f, 0.f};

    const int srow = wave * 32 + (lane >> 2);   // +16 for second call
    const int scol = (lane & 3) * 8;

    for (int k0 = 0; k0 < CDIM; k0 += 32) {
        __syncthreads();
#pragma unroll
        for (int c = 0; c < 2; c++) {
            gll16(A + (size_t)(rblk * 128 + srow + c * 16) * CDIM + k0 + scol,
                  &As[srow + c * 16][scol]);
            gll16(BT + (size_t)(cblk * 128 + srow + c * 16) * CDIM + k0 + scol,
                  &Bs[srow + c * 16][scol]);
        }
        __syncthreads();

        short8 af[4], bfr[4];
#pragma unroll
        for (int i = 0; i < 4; i++)
            af[i] = *(const short8*)&As[wr * 64 + i * 16 + l15][quad * 8];
#pragma unroll
        for (int j = 0; j < 4; j++)
            bfr[j] = *(const short8*)&Bs[wc * 64 + j * 16 + l15][quad * 8];
#pragma unroll
        for (int i = 0; i < 4; i++)
#pragma unroll
            for (int j = 0; j < 4; j++)
                acc[i][j] = __builtin_amdgcn_mfma_f32_16x16x32_bf16(af[i], bfr[j], acc[i][j], 0, 0, 0);
    }

    // epilogue: bias + per-head LayerNorm + 0.125 attn scale
    const int col0 = cblk * 128 + wc * 64;
    const int h = col0 >> 6;
    float bv[4], gv[4], btv[4];
#pragma unroll
    for (int j = 0; j < 4; j++) {
        int d = j * 16 + l15;
        bv[j] = bias[col0 + d];
        gv[j] = gamma[d];
        btv[j] = beta[d];
    }
#pragma unroll
    for (int i = 0; i < 4; i++) {
        int rowl = rblk * 128 + wr * 64 + i * 16 + quad * 4;
#pragma unroll
        for (int reg = 0; reg < 4; reg++) {
            float x[4], s = 0.f, s2 = 0.f;
#pragma unroll
            for (int j = 0; j < 4; j++) {
                x[j] = acc[i][j][reg] + bv[j];
                s += x[j];
                s2 += x[j] * x[j];
            }
#pragma unroll
            for (int m = 1; m < 16; m <<= 1) {
                s += __shfl_xor(s, m);
                s2 += __shfl_xor(s2, m);
            }
            float mean = s * (1.f / 64.f);
            float var = s2 * (1.f / 64.f) - mean * mean;
            float rstd = rsqrtf(var + 1e-5f);
            int r = rowl + reg;
            int b = r >> 11, n = r & (SEQ - 1);
            size_t base = (((size_t)b * NHEADS + h) * SEQ + n) * 64;
#pragma unroll
            for (int j = 0; j < 4; j++) {
                float y = ((x[j] - mean) * rstd * gv[j] + btv[j]) * 0.125f;
                Out[base + j * 16 + l15] = f2bf(y);
            }
        }
    }
}

// KV variant: K-blocks (cblk<8): LN -> kln [bh][n][d].
// V-blocks (cblk>=8): bias -> wave-local LDS transpose -> VT [bh][d][n].
__global__ __launch_bounds__(256) void gemm_kv(
    const short* __restrict__ A,     // [8192][1024] bf16
    const short* __restrict__ BT,    // [2048][1024] bf16 (Wkv^T)
    const float* __restrict__ bias,  // [2048]
    const float* __restrict__ gamma, // [64]
    const float* __restrict__ beta,  // [64]
    short* __restrict__ KOut,        // [B][H][N][64] bf16
    short* __restrict__ VT)          // [B][H][64][N] bf16
{
    __shared__ short As[128][32];
    __shared__ short Bs[128][32];
    __shared__ short Ts[4][64][68];  // V transpose scratch (wave-local)

    const int tid = threadIdx.x;
    const int wave = tid >> 6, lane = tid & 63;
    const int wr = wave >> 1, wc = wave & 1;
    const int quad = lane >> 4, l15 = lane & 15;
    const int rblk = blockIdx.y, cblk = blockIdx.x;

    f32x4 acc[4][4];
#pragma unroll
    for (int i = 0; i < 4; i++)
#pragma unroll
        for (int j = 0; j < 4; j++) acc[i][j] = f32x4{0.f, 0.f, 0.f, 0.f};

    const int srow = wave * 32 + (lane >> 2);
    const int scol = (lane & 3) * 8;

    for (int k0 = 0; k0 < CDIM; k0 += 32) {
        __syncthreads();
#pragma unroll
        for (int c = 0; c < 2; c++) {
            gll16(A + (size_t)(rblk * 128 + srow + c * 16) * CDIM + k0 + scol,
                  &As[srow + c * 16][scol]);
            gll16(BT + (size_t)(cblk * 128 + srow + c * 16) * CDIM + k0 + scol,
                  &Bs[srow + c * 16][scol]);
        }
        __syncthreads();

        short8 af[4], bfr[4];
#pragma unroll
        for (int i = 0; i < 4; i++)
            af[i] = *(const short8*)&As[wr * 64 + i * 16 + l15][quad * 8];
#pragma unroll
        for (int j = 0; j < 4; j++)
            bfr[j] = *(const short8*)&Bs[wc * 64 + j * 16 + l15][quad * 8];
#pragma unroll
        for (int i = 0; i < 4; i++)
#pragma unroll
            for (int j = 0; j < 4; j++)
                acc[i][j] = __builtin_amdgcn_mfma_f32_16x16x32_bf16(af[i], bfr[j], acc[i][j], 0, 0, 0);
    }

    const int col0 = cblk * 128 + wc * 64;
    const int g = col0 >> 6;  // 0..31, block-uniform K/V split
    float bv[4];
#pragma unroll
    for (int j = 0; j < 4; j++) bv[j] = bias[col0 + j * 16 + l15];

    if (g < NHEADS) {  // K path with LayerNorm
        const int h = g;
        float gv[4], btv[4];
#pragma unroll
        for (int j = 0; j < 4; j++) {
            int d = j * 16 + l15;
            gv[j] = gamma[d];
            btv[j] = beta[d];
        }
#pragma unroll
        for (int i = 0; i < 4; i++) {
            int rowl = rblk * 128 + wr * 64 + i * 16 + quad * 4;
#pragma unroll
            for (int reg = 0; reg < 4; reg++) {
                float x[4], s = 0.f, s2 = 0.f;
#pragma unroll
                for (int j = 0; j < 4; j++) {
                    x[j] = acc[i][j][reg] + bv[j];
                    s += x[j];
                    s2 += x[j] * x[j];
                }
#pragma unroll
                for (int m = 1; m < 16; m <<= 1) {
                    s += __shfl_xor(s, m);
                    s2 += __shfl_xor(s2, m);
                }
                float mean = s * (1.f / 64.f);
                float var = s2 * (1.f / 64.f) - mean * mean;
                float rstd = rsqrtf(var + 1e-5f);
                int r = rowl + reg;
                int b = r >> 11, n = r & (SEQ - 1);
                size_t base = (((size_t)b * NHEADS + h) * SEQ + n) * 64;
#pragma unroll
                for (int j = 0; j < 4; j++) {
                    float y = (x[j] - mean) * rstd * gv[j] + btv[j];
                    KOut[base + j * 16 + l15] = f2bf(y);
                }
            }
        }
    } else {  // V path: bias, wave-local transpose, write V^T coalesced
        const int h = g - NHEADS;
        // stage into Ts[wave][n_local][d]
#pragma unroll
        for (int i = 0; i < 4; i++)
#pragma unroll
            for (int reg = 0; reg < 4; reg++)
#pragma unroll
                for (int j = 0; j < 4; j++)
                    Ts[wave][i * 16 + quad * 4 + reg][j * 16 + l15] =
                        f2bf(acc[i][j][reg] + bv[j]);
        // wave-local: LDS write->read ordering handled by compiler waitcnt
        const int r = rblk * 128 + wr * 64 + lane;  // global row (n)
        const int b = r >> 11, n = r & (SEQ - 1);
        const size_t vtbase = (((size_t)b * NHEADS + h) * 64) * SEQ;
#pragma unroll
        for (int e8 = 0; e8 < 8; e8++) {
            short8 v = *(const short8*)&Ts[wave][lane][e8 * 8];
#pragma unroll
            for (int e = 0; e < 8; e++)
                VT[vtbase + (size_t)(e8 * 8 + e) * SEQ + n] = v[e];
        }
    }
}

// ---------------------------------------------------------------------------
// Flash attention v2: 64 q-rows/block, 128-key tiles (16 iters, 2 barriers).
// No running max (scores bounded by LN), l via ones-MFMA, V^T staged direct.
// ---------------------------------------------------------------------------
__global__ __launch_bounds__(256) void attn_fa(
    const short* __restrict__ Q,   // [B][H][N][64] bf16, pre-scaled 1/8
    const short* __restrict__ Kk,  // [B][H][N][64] bf16
    const short* __restrict__ VT,  // [B][H][64][N] bf16
    float* __restrict__ Out)       // [B][N][1024] fp32
{
    __shared__ short Ks[128][72];
    __shared__ short Vt[64][136];
    __shared__ short Ps[4][16][136];

    const int tid = threadIdx.x;
    const int wave = tid >> 6, lane = tid & 63;
    const int quad = lane >> 4, l15 = lane & 15;
    const int bh = blockIdx.y;
    const int b = bh >> 4, h = bh & 15;
    const int qt = blockIdx.x;
    const size_t head_base = (size_t)bh * SEQ * 64;
    const size_t vt_base = (size_t)bh * 64 * SEQ;

    const int qrow = qt * 64 + wave * 16 + l15;
    const short8 qf0 = *(const short8*)(Q + head_base + (size_t)qrow * 64 + quad * 8);
    const short8 qf1 = *(const short8*)(Q + head_base + (size_t)qrow * 64 + 32 + quad * 8);

    short8 ones;
#pragma unroll
    for (int e = 0; e < 8; e++) ones[e] = (short)0x3F80;  // bf16 1.0

    f32x4 o[4];
#pragma unroll
    for (int jd = 0; jd < 4; jd++) o[jd] = f32x4{0.f, 0.f, 0.f, 0.f};
    f32x4 osum = f32x4{0.f, 0.f, 0.f, 0.f};

    const int ks_key = tid >> 1, ks_c = (tid & 1) * 4;   // 4 chunks of 16B
    const int vt_d = tid >> 2, vt_c = (tid & 3) * 4;     // 4 chunks of 16B

    for (int kt = 0; kt < 16; kt++) {
        short8 kv[4], vv[4];
        const short* kg = Kk + head_base + (size_t)(kt * 128 + ks_key) * 64 + ks_c * 8;
        const short* vg = VT + vt_base + (size_t)vt_d * SEQ + kt * 128 + vt_c * 8;
#pragma unroll
        for (int i = 0; i < 4; i++) kv[i] = ((const short8*)kg)[i];
#pragma unroll
        for (int i = 0; i < 4; i++) vv[i] = ((const short8*)vg)[i];

        __syncthreads();  // prior iteration's frag reads done
#pragma unroll
        for (int i = 0; i < 4; i++) *(short8*)&Ks[ks_key][(ks_c + i) * 8] = kv[i];
#pragma unroll
        for (int i = 0; i < 4; i++) *(short8*)&Vt[vt_d][(vt_c + i) * 8] = vv[i];
        __syncthreads();

        // S = Q K^T (8 key-tiles of 16)
        f32x4 s[8];
#pragma unroll
        for (int jk = 0; jk < 8; jk++) {
            short8 kf0 = *(const short8*)&Ks[jk * 16 + l15][quad * 8];
            short8 kf1 = *(const short8*)&Ks[jk * 16 + l15][32 + quad * 8];
            f32x4 z = f32x4{0.f, 0.f, 0.f, 0.f};
            z = __builtin_amdgcn_mfma_f32_16x16x32_bf16(qf0, kf0, z, 0, 0, 0);
            z = __builtin_amdgcn_mfma_f32_16x16x32_bf16(qf1, kf1, z, 0, 0, 0);
            s[jk] = z;
        }

        // P = exp(S) (no max subtraction; scores bounded), C-layout -> LDS
#pragma unroll
        for (int jk = 0; jk < 8; jk++)
#pragma unroll
            for (int reg = 0; reg < 4; reg++)
                Ps[wave][quad * 4 + reg][jk * 16 + l15] = f2bf(__expf(s[jk][reg]));

        // A-layout P frags (wave-local round trip, no barrier needed)
        short8 pf[4];
#pragma unroll
        for (int seg = 0; seg < 4; seg++)
            pf[seg] = *(const short8*)&Ps[wave][l15][seg * 32 + quad * 8];

        // l += row-sums via ones-MFMA; O += P V
#pragma unroll
        for (int seg = 0; seg < 4; seg++)
            osum = __builtin_amdgcn_mfma_f32_16x16x32_bf16(pf[seg], ones, osum, 0, 0, 0);
#pragma unroll
        for (int seg = 0; seg < 4; seg++)
#pragma unroll
            for (int jd = 0; jd < 4; jd++) {
                short8 vf = *(const short8*)&Vt[jd * 16 + l15][seg * 32 + quad * 8];
                o[jd] = __builtin_amdgcn_mfma_f32_16x16x32_bf16(pf[seg], vf, o[jd], 0, 0, 0);
            }
    }

    // epilogue: O / l, write [B][N][C] fp32
#pragma unroll
    for (int reg = 0; reg < 4; reg++) {
        float inv = 1.f / osum[reg];
        int r = qt * 64 + wave * 16 + quad * 4 + reg;
        size_t base = ((size_t)b * SEQ + r) * CDIM + h * 64;
#pragma unroll
        for (int jd = 0; jd < 4; jd++)
            Out[base + jd * 16 + l15] = o[jd][reg] * inv;
    }
}

extern "C" void kernel_launch(void* const* d_in, const int* in_sizes, int n_in,
                              void* d_out, int out_size, void* d_ws, size_t ws_size,
                              hipStream_t stream) {
    const float* x1 = (const float*)d_in[0];
    const float* x2 = (const float*)d_in[1];
    const float* wq = (const float*)d_in[2];
    const float* bq = (const float*)d_in[3];
    const float* wkv = (const float*)d_in[4];
    const float* bkv = (const float*)d_in[5];
    const float* gq = (const float*)d_in[6];
    const float* btq = (const float*)d_in[7];
    const float* gk = (const float*)d_in[8];
    const float* btk = (const float*)d_in[9];
    float* out = (float*)d_out;

    short* a1 = (short*)d_ws;                          // [8192][1024] bf16
    short* a2 = a1 + (size_t)ROWS * CDIM;              // [8192][1024]
    short* wqT = a2 + (size_t)ROWS * CDIM;             // [1024][1024]
    short* wkvT = wqT + (size_t)CDIM * CDIM;           // [2048][1024]
    short* qln = wkvT + (size_t)2 * CDIM * CDIM;       // [B][H][N][64]
    short* kln = qln + (size_t)ROWS * CDIM;            // [B][H][N][64]
    short* vt = kln + (size_t)ROWS * CDIM;             // [B][H][64][N]

    const int n8 = ROWS * CDIM / 8;
    cvt_bf16<<<dim3(n8 / 256), 256, 0, stream>>>(x1, a1, n8);
    cvt_bf16<<<dim3(n8 / 256), 256, 0, stream>>>(x2, a2, n8);
    wtrans<<<dim3(16, 16), 256, 0, stream>>>(wq, wqT, CDIM);
    wtrans<<<dim3(32, 16), 256, 0, stream>>>(wkv, wkvT, 2 * CDIM);

    gemm_q_ln<<<dim3(8, 64), 256, 0, stream>>>(a1, wqT, bq, gq, btq, qln);
    gemm_kv<<<dim3(16, 64), 256, 0, stream>>>(a2, wkvT, bkv, gk, btk, kln, vt);
    attn_fa<<<dim3(32, 64), 256, 0, stream>>>(qln, kln, vt, out);
}